// Round 1
// baseline (466.481 us; speedup 1.0000x reference)
//
#include <hip/hip_runtime.h>
#include <math.h>

#define B_ 2
#define S_ 2048
#define D_ 2048
#define H_ 16
#define QLORA 1536
#define KVLORA 512
#define DN 128
#define DR 64
#define DQK 192
#define DV 128
#define EPSF 1e-6f
#define SCALEF 0.07216878364870322f   // 192^-0.5

typedef short short8 __attribute__((ext_vector_type(8)));
typedef float float4v __attribute__((ext_vector_type(4)));

__device__ __forceinline__ unsigned short f2bf(float f) {
    union { float f; unsigned u; } x; x.f = f;
    unsigned r = x.u + 0x7fffu + ((x.u >> 16) & 1u);   // RNE
    return (unsigned short)(r >> 16);
}
__device__ __forceinline__ float bf2f(unsigned short u) {
    union { unsigned u; float f; } x; x.u = (unsigned)u << 16;
    return x.f;
}

// async global->LDS, 16B per lane; LDS dest = wave-uniform base + lane*16
#define GLD16(src, dst)                                                        \
    __builtin_amdgcn_global_load_lds(                                          \
        (const __attribute__((address_space(1))) void*)(src),                  \
        (__attribute__((address_space(3))) void*)(dst), 16, 0, 0)

// ---------------------------------------------------------------------------
// all fp32->bf16 conversions in ONE launch (6 ranges, if-chain)
// ---------------------------------------------------------------------------
__global__ __launch_bounds__(256) void conv_all(
        const float* __restrict__ s0, unsigned short* __restrict__ d0, long e0,
        const float* __restrict__ s1, unsigned short* __restrict__ d1, long e1,
        const float* __restrict__ s2, unsigned short* __restrict__ d2, long e2,
        const float* __restrict__ s3, unsigned short* __restrict__ d3, long e3,
        const float* __restrict__ s4, unsigned short* __restrict__ d4, long e4,
        const float* __restrict__ s5, unsigned short* __restrict__ d5) {
    long c = (long)blockIdx.x * 256 + threadIdx.x;   // 8-elem chunk index
    const float* src;
    unsigned short* dst;
    if      (c < e0) { src = s0; dst = d0; }
    else if (c < e1) { src = s1; dst = d1; c -= e0; }
    else if (c < e2) { src = s2; dst = d2; c -= e1; }
    else if (c < e3) { src = s3; dst = d3; c -= e2; }
    else if (c < e4) { src = s4; dst = d4; c -= e3; }
    else             { src = s5; dst = d5; c -= e4; }
    const float* p = src + c * 8;
    float4 a = *(const float4*)(p);
    float4 b = *(const float4*)(p + 4);
    union { short8 v; unsigned short u[8]; } t;
    t.u[0] = f2bf(a.x); t.u[1] = f2bf(a.y); t.u[2] = f2bf(a.z); t.u[3] = f2bf(a.w);
    t.u[4] = f2bf(b.x); t.u[5] = f2bf(b.y); t.u[6] = f2bf(b.z); t.u[7] = f2bf(b.w);
    *(short8*)&dst[c * 8] = t.v;
}

// ---------------------------------------------------------------------------
// bf16 MFMA GEMM:  C[M,N] = A[M,K] @ W[N,K]^T; OT = float or ushort(bf16) out.
// 128x128 tile, BK=64; global_load_lds width=16 staging with XOR swizzle.
// ---------------------------------------------------------------------------
#define GBM 128
#define GBN 128
#define GBK 64

template <typename OT>
__global__ __launch_bounds__(256) void gemm_t(const unsigned short* __restrict__ A,
                                              const unsigned short* __restrict__ W,
                                              OT* __restrict__ C,
                                              int M, int N, int K) {
    __shared__ unsigned short As[GBM * GBK];   // 16384 B
    __shared__ unsigned short Ws[GBN * GBK];   // 16384 B

    const int tid = threadIdx.x;
    const int w = tid >> 6, lane = tid & 63;
    const int l16 = lane & 15, quad = lane >> 4;
    const int wm = (w >> 1) * 64, wn = (w & 1) * 64;
    const int row0 = blockIdx.y * GBM, col0 = blockIdx.x * GBN;

    const int rL  = lane >> 3;
    const int c8g = (lane & 7) ^ rL;
    const int swzk[2] = { (((0 * 4) + quad) ^ (l16 & 7)) * 8,
                          (((1 * 4) + quad) ^ (l16 & 7)) * 8 };

    const float4v zf = {0.f, 0.f, 0.f, 0.f};
    float4v acc[4][4] = {{zf, zf, zf, zf}, {zf, zf, zf, zf},
                         {zf, zf, zf, zf}, {zf, zf, zf, zf}};

    for (int k0 = 0; k0 < K; k0 += GBK) {
        __syncthreads();
#pragma unroll
        for (int j = 0; j < 4; ++j) {
            const int ch = w * 4 + j;
            const int r = ch * 8 + rL;
            GLD16(&A[(size_t)(row0 + r) * K + k0 + c8g * 8], &As[ch * 512]);
            GLD16(&W[(size_t)(col0 + r) * K + k0 + c8g * 8], &Ws[ch * 512]);
        }
        __syncthreads();

#pragma unroll
        for (int kk = 0; kk < 2; ++kk) {
            const int swz = swzk[kk];
            short8 af[4], bf[4];
#pragma unroll
            for (int mi = 0; mi < 4; ++mi)
                af[mi] = *(const short8*)&As[(wm + mi * 16 + l16) * GBK + swz];
#pragma unroll
            for (int ni = 0; ni < 4; ++ni)
                bf[ni] = *(const short8*)&Ws[(wn + ni * 16 + l16) * GBK + swz];
#pragma unroll
            for (int mi = 0; mi < 4; ++mi)
#pragma unroll
                for (int ni = 0; ni < 4; ++ni)
                    acc[mi][ni] = __builtin_amdgcn_mfma_f32_16x16x32_bf16(af[mi], bf[ni], acc[mi][ni], 0, 0, 0);
        }
    }

#pragma unroll
    for (int mi = 0; mi < 4; ++mi)
#pragma unroll
        for (int ni = 0; ni < 4; ++ni)
#pragma unroll
            for (int r = 0; r < 4; ++r) {
                size_t idx = (size_t)(row0 + wm + mi * 16 + quad * 4 + r) * N + col0 + wn + ni * 16 + l16;
                if constexpr (sizeof(OT) == 2) C[idx] = f2bf(acc[mi][ni][r]);
                else                           C[idx] = acc[mi][ni][r];
            }
}

// ---------------------------------------------------------------------------
__global__ __launch_bounds__(256) void rmsnorm_b(const float* __restrict__ X,
                                                 const float* __restrict__ w,
                                                 unsigned short* __restrict__ Y,
                                                 int n, int ld) {
    __shared__ float tmp[4];
    const int row = blockIdx.x;
    const int tid = threadIdx.x;
    const float* x = X + (size_t)row * ld;

    float ss = 0.f;
    for (int c = tid; c < n; c += 256) {
        float v = x[c];
        ss = fmaf(v, v, ss);
    }
#pragma unroll
    for (int off = 32; off; off >>= 1) ss += __shfl_xor(ss, off, 64);
    if ((tid & 63) == 0) tmp[tid >> 6] = ss;
    __syncthreads();
    ss = tmp[0] + tmp[1] + tmp[2] + tmp[3];
    float r = rsqrtf(ss / (float)n + EPSF);

    for (int c = tid; c < n; c += 256)
        Y[(size_t)row * n + c] = f2bf(x[c] * r * w[c]);
}

// ---------------------------------------------------------------------------
__global__ __launch_bounds__(256) void kv_post(const float* __restrict__ KV,
                                               const float* __restrict__ w,
                                               const float* __restrict__ fc,
                                               unsigned short* __restrict__ kvcb,
                                               float* __restrict__ kpe,
                                               int ldkv) {
    __shared__ float tmp[4];
    const int row = blockIdx.x;
    const int s = row & (S_ - 1);
    const int tid = threadIdx.x;
    const float* kv = KV + (size_t)row * ldkv;

    float ss = 0.f;
#pragma unroll
    for (int c = tid; c < KVLORA; c += 256) {
        float v = kv[c];
        ss = fmaf(v, v, ss);
    }
#pragma unroll
    for (int off = 32; off; off >>= 1) ss += __shfl_xor(ss, off, 64);
    if ((tid & 63) == 0) tmp[tid >> 6] = ss;
    __syncthreads();
    ss = tmp[0] + tmp[1] + tmp[2] + tmp[3];
    float r = rsqrtf(ss / (float)KVLORA + EPSF);

#pragma unroll
    for (int c = tid; c < KVLORA; c += 256)
        kvcb[(size_t)row * KVLORA + c] = f2bf(kv[c] * r * w[c]);

    if (tid < 32) {
        int i = tid;
        float c0 = fc[(s * 32 + i) * 2 + 0];
        float s0 = fc[(s * 32 + i) * 2 + 1];
        float x0 = kv[KVLORA + 2 * i];
        float x1 = kv[KVLORA + 2 * i + 1];
        kpe[(size_t)row * DR + 2 * i]     = x0 * c0 - x1 * s0;
        kpe[(size_t)row * DR + 2 * i + 1] = x0 * s0 + x1 * c0;
    }
}

// ---------------------------------------------------------------------------
// pack_k: Kbf (B,H,S,192) bf16 from kvbb (M,H*256) bf16 + kpe (M,64) fp32
// ---------------------------------------------------------------------------
__global__ __launch_bounds__(256) void pack_k(const unsigned short* __restrict__ kvbb,
                                              const float* __restrict__ kpe,
                                              unsigned short* __restrict__ Kbf) {
    const int c = blockIdx.x * 256 + threadIdx.x;   // chunk of 8 elems
    const int total = B_ * H_ * S_ * (DQK / 8);
    if (c >= total) return;
    const int d8 = c % (DQK / 8);
    const int hs = c / (DQK / 8);
    const int s  = hs % S_;
    const int bh = hs / S_;
    const int b  = bh / H_;
    const int h  = bh % H_;
    const int d  = d8 * 8;
    const int row = b * S_ + s;

    short8 v;
    if (d < DN) {
        v = *(const short8*)&kvbb[(size_t)row * (H_ * 256) + h * 256 + d];
    } else {
        const float* src = kpe + (size_t)row * DR + (d - DN);
        float4 a = *(const float4*)(src);
        float4 bb = *(const float4*)(src + 4);
        union { short8 v; unsigned short u[8]; } t;
        t.u[0] = f2bf(a.x);  t.u[1] = f2bf(a.y);  t.u[2] = f2bf(a.z);  t.u[3] = f2bf(a.w);
        t.u[4] = f2bf(bb.x); t.u[5] = f2bf(bb.y); t.u[6] = f2bf(bb.z); t.u[7] = f2bf(bb.w);
        v = t.v;
    }
    *(short8*)&Kbf[(size_t)c * 8] = v;
}

// ---------------------------------------------------------------------------
// pack_vt: Vt (B,H,128,S) bf16 from kvbb (M,H*256) bf16 cols h*256+128..+256
// ---------------------------------------------------------------------------
__global__ __launch_bounds__(256) void pack_vt(const unsigned short* __restrict__ kvbb,
                                               unsigned short* __restrict__ Vt) {
    __shared__ unsigned short T[DV][72];
    const int st = blockIdx.x;            // seq tile (64)
    const int bh = blockIdx.y;            // b*H+h
    const int b = bh >> 4, h = bh & 15;
    const int s0 = st * 64;
    const int tid = threadIdx.x;

    for (int c = tid; c < 64 * 16; c += 256) {
        int sp = c >> 4, ch = c & 15;
        short8 v = *(const short8*)&kvbb[(size_t)(b * S_ + s0 + sp) * (H_ * 256) + h * 256 + DN + ch * 8];
        union { short8 v; unsigned short u[8]; } t; t.v = v;
        int dv = ch * 8;
#pragma unroll
        for (int e = 0; e < 8; ++e) T[dv + e][sp] = t.u[e];
    }
    __syncthreads();
    for (int c = tid; c < 128 * 8; c += 256) {
        int dv = c >> 3, ch = c & 7;
        *(short8*)&Vt[((size_t)bh * DV + dv) * S_ + s0 + ch * 8] = *(short8*)&T[dv][ch * 8];
    }
}

// ---------------------------------------------------------------------------
// MFMA flash attention (causal), bf16 in (q with fused RoPE), fp32 acc.
//
// v2 (LDS-bandwidth fix):
//  - 128-row q-tile per block, 4 waves x 32 q-rows (2 A-frag groups/wave):
//    each full K/V LDS tile read now feeds 2x the MFMAs (LDS bytes/FLOP /2).
//  - K/V staged via global_load_lds(16B) into FLAT LDS with GEMM-style XOR
//    chunk swizzle (c ^ (row&7)) -> bank-uniform ds_read_b128 B-frags, no
//    pads, no reg-staging (saves 41KB/tile of LDS write instr traffic).
//  - double-buffered K/V (2x(24+16)KB) + raw s_barrier + counted vmcnt(10):
//    next tile's 10 DMA loads stay in flight across the barrier (no vmcnt(0)
//    drain mid-loop).
//  - Ps is wave-private: no barrier between softmax and PV.
//  - grid x=bh (same-bh blocks land on same XCD: ids differ by 32 ≡ 0 mod 8),
//    y=pair 0..7 over 16 q-tiles (qt = y and 15-y -> 34 k-tiles/block, flat).
// ---------------------------------------------------------------------------
#define QTILES 16   // 2048 / 128

__global__ __launch_bounds__(256, 1) void flash_mfma(const unsigned short* __restrict__ Qb,
                                                     const float* __restrict__ fc,
                                                     const unsigned short* __restrict__ Kbf,
                                                     const unsigned short* __restrict__ Vt,
                                                     unsigned short* __restrict__ Ob) {
    __shared__ unsigned short Ks[2][64 * 192];    // 2 x 24576 B, swizzled chunks
    __shared__ unsigned short Vs[2][128 * 64];    // 2 x 16384 B, swizzled chunks
    __shared__ unsigned short Ps[4][32][72];      // 18432 B, wave-private P

    const int bh = blockIdx.x;                  // b*H+h
    const int bx = blockIdx.y;                  // 0..7 pair index
    const int b = bh >> 4, h = bh & 15;
    const int tid = threadIdx.x;
    const int w = tid >> 6, lane = tid & 63;
    const int l16 = lane & 15, quad = lane >> 4;
    const int sw = l16 & 7;                     // read-side swizzle key

    const unsigned short* Kg = Kbf + (size_t)bh * S_ * DQK;
    const unsigned short* Vg = Vt + (size_t)bh * DV * S_;

    // stage K/V tile kt_ into buffer bufi: 10 global_load_lds per wave.
    // chunk c of row r stored at (r*chunks_per_row + (c ^ (r&7))) * 16B.
    auto stage = [&](int kt_, int bufi) {
        const int kb_ = kt_ * 64;
#pragma unroll
        for (int i_ = 0; i_ < 6; ++i_) {             // K: 64 rows x 24 chunks
            int ch = (w * 6 + i_) * 64 + lane;
            int r_ = ch / 24, c_ = ch - r_ * 24;
            GLD16(&Kg[(size_t)(kb_ + r_) * DQK + ((c_ ^ (r_ & 7)) << 3)],
                  &Ks[bufi][(w * 6 + i_) * 512]);
        }
#pragma unroll
        for (int i_ = 0; i_ < 4; ++i_) {             // V: 128 rows x 8 chunks
            int ch = (w * 4 + i_) * 64 + lane;
            int r_ = ch >> 3, c_ = ch & 7;
            GLD16(&Vg[(size_t)r_ * S_ + kb_ + ((c_ ^ (r_ & 7)) << 3)],
                  &Vs[bufi][(w * 4 + i_) * 512]);
        }
    };

    for (int half = 0; half < 2; ++half) {
        const int qt = half ? (QTILES - 1 - bx) : bx;
        const int q0 = qt * 128;
        const int ntiles = 2 * qt + 2;          // always even -> buf parity ok
        const int wr0 = q0 + w * 32;            // wave's first q row

        stage(0, 0);                            // tile 0 DMA in flight

        // Q A-frags (2 groups of 16 rows), RoPE fused for d >= 128
        short8 a_q[2][6];
#pragma unroll
        for (int g = 0; g < 2; ++g) {
            const int s = wr0 + g * 16 + l16;
            const unsigned short* qrow = Qb + (size_t)(b * S_ + s) * (H_ * DQK) + h * DQK;
#pragma unroll
            for (int i = 0; i < 6; ++i) {
                short8 t = *(const short8*)&qrow[i * 32 + quad * 8];
                if (i >= 4) {
                    union { short8 v; unsigned short u[8]; } x; x.v = t;
#pragma unroll
                    for (int j = 0; j < 4; ++j) {
                        int ip = (i - 4) * 16 + quad * 4 + j;
                        float c0 = fc[(s * 32 + ip) * 2 + 0];
                        float s0 = fc[(s * 32 + ip) * 2 + 1];
                        float x0 = bf2f(x.u[2 * j]);
                        float x1 = bf2f(x.u[2 * j + 1]);
                        x.u[2 * j]     = f2bf(x0 * c0 - x1 * s0);
                        x.u[2 * j + 1] = f2bf(x0 * s0 + x1 * c0);
                    }
                    t = x.v;
                }
                a_q[g][i] = t;
            }
        }

        const float4v zf = {0.f, 0.f, 0.f, 0.f};
        float4v o_acc[2][8] = {{zf, zf, zf, zf, zf, zf, zf, zf},
                               {zf, zf, zf, zf, zf, zf, zf, zf}};
        float l_r[2][4] = {{0.f, 0.f, 0.f, 0.f}, {0.f, 0.f, 0.f, 0.f}};

        int buf = 0;
        for (int kt = 0; kt < ntiles; ++kt) {
            const int kb = kt * 64;

            // barrier 1: everyone done computing kt-1 -> buf^1 overwritable
            __builtin_amdgcn_s_barrier();
            if (kt + 1 < ntiles) {
                stage(kt + 1, buf ^ 1);
                asm volatile("s_waitcnt vmcnt(10)" ::: "memory");  // own kt loads done
            } else {
                asm volatile("s_waitcnt vmcnt(0)" ::: "memory");
            }
            __builtin_amdgcn_sched_barrier(0);
            // barrier 2: everyone's kt loads landed
            __builtin_amdgcn_s_barrier();
            __builtin_amdgcn_sched_barrier(0);

            if (kb <= wr0 + 31) {               // wave not fully causal-masked
                const unsigned short* Kb_ = Ks[buf];
                const unsigned short* Vb_ = Vs[buf];

                // QK^T: 24 ds_read_b128 -> 48 mfma (8 independent acc chains)
                float4v sc[2][4] = {{zf, zf, zf, zf}, {zf, zf, zf, zf}};
#pragma unroll
                for (int i = 0; i < 6; ++i) {
                    short8 bk[4];
#pragma unroll
                    for (int kg = 0; kg < 4; ++kg)
                        bk[kg] = *(const short8*)&Kb_[(kg * 16 + l16) * 192 + (((i * 4 + quad) ^ sw) << 3)];
#pragma unroll
                    for (int kg = 0; kg < 4; ++kg) {
                        sc[0][kg] = __builtin_amdgcn_mfma_f32_16x16x32_bf16(a_q[0][i], bk[kg], sc[0][kg], 0, 0, 0);
                        sc[1][kg] = __builtin_amdgcn_mfma_f32_16x16x32_bf16(a_q[1][i], bk[kg], sc[1][kg], 0, 0, 0);
                    }
                }

                // max-free softmax (mask post-exp; wave-uniform mneed branch)
#pragma unroll
                for (int g = 0; g < 2; ++g) {
                    const int rg0 = wr0 + g * 16;
                    const bool mneed = (kb + 63 > rg0);
#pragma unroll
                    for (int kg = 0; kg < 4; ++kg) {
                        const int key = kb + kg * 16 + l16;
#pragma unroll
                        for (int r = 0; r < 4; ++r) {
                            float p = __expf(sc[g][kg][r] * SCALEF);
                            if (mneed && key > rg0 + quad * 4 + r) p = 0.f;
                            l_r[g][r] += p;
                            Ps[w][g * 16 + quad * 4 + r][kg * 16 + l16] = f2bf(p);
                        }
                    }
                }

                // PV: Ps is wave-private -> no barrier needed before reads
#pragma unroll
                for (int kc = 0; kc < 2; ++kc) {
                    short8 pa0 = *(const short8*)&Ps[w][l16][kc * 32 + quad * 8];
                    short8 pa1 = *(const short8*)&Ps[w][16 + l16][kc * 32 + quad * 8];
#pragma unroll
                    for (int dvt = 0; dvt < 8; ++dvt) {
                        short8 vb = *(const short8*)&Vb_[(dvt * 16 + l16) * 64 + (((kc * 4 + quad) ^ sw) << 3)];
                        o_acc[0][dvt] = __builtin_amdgcn_mfma_f32_16x16x32_bf16(pa0, vb, o_acc[0][dvt], 0, 0, 0);
                        o_acc[1][dvt] = __builtin_amdgcn_mfma_f32_16x16x32_bf16(pa1, vb, o_acc[1][dvt], 0, 0, 0);
                    }
                }
            }
            buf ^= 1;
        }

        // epilogue: reduce l over the 16 key-lanes, write O
#pragma unroll
        for (int g = 0; g < 2; ++g)
#pragma unroll
            for (int r = 0; r < 4; ++r) {
                float t = l_r[g][r];
                t += __shfl_xor(t, 1);
                t += __shfl_xor(t, 2);
                t += __shfl_xor(t, 4);
                t += __shfl_xor(t, 8);
                l_r[g][r] = t;
            }
#pragma unroll
        for (int g = 0; g < 2; ++g)
#pragma unroll
            for (int r = 0; r < 4; ++r) {
                float inv = 1.f / l_r[g][r];
                int row = wr0 + g * 16 + quad * 4 + r;
                unsigned short* op = Ob + (size_t)(b * S_ + row) * (H_ * DV) + h * DV;
#pragma unroll
                for (int dvt = 0; dvt < 8; ++dvt)
                    op[dvt * 16 + l16] = f2bf(o_acc[g][dvt][r] * inv);
            }
    }
}

// ---------------------------------------------------------------------------
extern "C" void kernel_launch(void* const* d_in, const int* in_sizes, int n_in,
                              void* d_out, int out_size, void* d_ws, size_t ws_size,
                              hipStream_t stream) {
    const float* x    = (const float*)d_in[0];
    const float* fc   = (const float*)d_in[1];
    const float* Wqa  = (const float*)d_in[2];
    const float* qlw  = (const float*)d_in[3];
    const float* Wqb  = (const float*)d_in[4];
    const float* Wkva = (const float*)d_in[5];
    const float* kvw  = (const float*)d_in[6];
    const float* Wkvb = (const float*)d_in[7];
    const float* Wo   = (const float*)d_in[8];
    float* out = (float*)d_out;

    const int M = B_ * S_;                 // 4096
    const int NQKV = QLORA + 640;          // 2176
    char* wsb = (char*)d_ws;

    // R1 (50331648 B): qb bf16 (25165824) + Wob (8388608)
    unsigned short* qb  = (unsigned short*)wsb;
    unsigned short* Wob = (unsigned short*)(wsb + 25165824);
    // R2 (67108864 B)
    char* R2 = wsb + 50331648;
    float*          qlkv  = (float*)R2;                          // 35651584
    unsigned short* xb    = (unsigned short*)(R2 + 35651584);    // 16777216
    unsigned short* Wcat  = (unsigned short*)(R2 + 52428800);    //  8912896
    unsigned short* kvbb  = (unsigned short*)R2;                 // 33554432 (after qlkv dead)
    unsigned short* attnb = (unsigned short*)R2;                 // 16777216 (after packs)
    // R3 (25165824 B)
    char* R3 = R2 + 67108864;
    unsigned short* qlatb = (unsigned short*)R3;                 // 12582912
    unsigned short* Wqbb  = (unsigned short*)(R3 + 12582912);    //  9437184
    unsigned short* Kbf   = (unsigned short*)R3;                 // 25165824 (after q-gemm)
    // R4 (16777216 B)
    char* R4 = R3 + 25165824;
    float*          kpe   = (float*)R4;                          //  1048576
    unsigned short* kvcb  = (unsigned short*)(R4 + 1048576);     //  4194304
    unsigned short* Wkvbb = (unsigned short*)(R4 + 5242880);     //  4194304
    unsigned short* Vt    = (unsigned short*)R4;                 // 16777216 (after pack_k)

    // 0) single mega-conversion: x, Wqa, Wkva, Wqb, Wkvb, Wo
    {
        const long e0 = 1048576;           // x      (M*D/8)
        const long e1 = e0 + 393216;       // Wqa    (1536*2048/8)
        const long e2 = e1 + 147456;       // Wkva   (576*2048/8)
        const long e3 = e2 + 589824;       // Wqb    (3072*1536/8)
        const long e4 = e3 + 262144;       // Wkvb   (4096*512/8)
        const long tot = e4 + 524288;      // Wo     (2048*2048/8) -> 2965504
        conv_all<<<(int)(tot / 256), 256, 0, stream>>>(
            x, xb, e0,
            Wqa, Wcat, e1,
            Wkva, Wcat + (size_t)QLORA * D_, e2,
            Wqb, Wqbb, e3,
            Wkvb, Wkvbb, e4,
            Wo, Wob);
    }

    // 1) merged: qlkv = xb @ Wcat^T (cols 0..1535 = qlat, 1536..2111 = kvraw)
    gemm_t<float><<<dim3(NQKV / GBN, M / GBM), 256, 0, stream>>>(xb, Wcat, qlkv, M, NQKV, D_);

    // 2) norms (emit bf16) + k_pe rope
    rmsnorm_b<<<M, 256, 0, stream>>>(qlkv, qlw, qlatb, QLORA, NQKV);
    kv_post<<<M, 256, 0, stream>>>(qlkv + QLORA, kvw, fc, kvcb, kpe, NQKV);

    // 3) qb = qlatb @ Wqbb^T (bf16 out; RoPE fused into flash Q load)
    //    kvbb = kvcb @ Wkvbb^T (bf16 out)
    gemm_t<unsigned short><<<dim3(H_ * DQK / GBN, M / GBM), 256, 0, stream>>>(qlatb, Wqbb, qb, M, H_ * DQK, QLORA);
    gemm_t<unsigned short><<<dim3(H_ * 256 / GBN, M / GBM), 256, 0, stream>>>(kvcb, Wkvbb, kvbb, M, H_ * 256, KVLORA);

    // 4) pack K then V (pack_k reads kpe which Vt overwrites -> strict order)
    {
        int total = B_ * H_ * S_ * (DQK / 8);
        pack_k<<<(total + 255) / 256, 256, 0, stream>>>(kvbb, kpe, Kbf);
        pack_vt<<<dim3(S_ / 64, B_ * H_), 256, 0, stream>>>(kvbb, Vt);
    }

    // 5) flash attention: 128-row q-tiles, pairs (bx, 15-bx) for balance
    flash_mfma<<<dim3(B_ * H_, QTILES / 2), 256, 0, stream>>>(qb, fc, Kbf, Vt, attnb);

    // 6) out = attnb @ Wob^T
    gemm_t<float><<<dim3(D_ / GBN, M / GBM), 256, 0, stream>>>(attnb, Wob, out, M, D_, D_);
}

// Round 2
// 451.437 us; speedup vs baseline: 1.0333x; 1.0333x over previous
//
#include <hip/hip_runtime.h>
#include <math.h>

#define B_ 2
#define S_ 2048
#define D_ 2048
#define H_ 16
#define QLORA 1536
#define KVLORA 512
#define DN 128
#define DR 64
#define DQK 192
#define DV 128
#define EPSF 1e-6f
#define SCALEF 0.07216878364870322f   // 192^-0.5

typedef short short8 __attribute__((ext_vector_type(8)));
typedef float float4v __attribute__((ext_vector_type(4)));

__device__ __forceinline__ unsigned short f2bf(float f) {
    union { float f; unsigned u; } x; x.f = f;
    unsigned r = x.u + 0x7fffu + ((x.u >> 16) & 1u);   // RNE
    return (unsigned short)(r >> 16);
}
__device__ __forceinline__ float bf2f(unsigned short u) {
    union { unsigned u; float f; } x; x.u = (unsigned)u << 16;
    return x.f;
}

// async global->LDS, 16B per lane; LDS dest = wave-uniform base + lane*16
#define GLD16(src, dst)                                                        \
    __builtin_amdgcn_global_load_lds(                                          \
        (const __attribute__((address_space(1))) void*)(src),                  \
        (__attribute__((address_space(3))) void*)(dst), 16, 0, 0)

// ---------------------------------------------------------------------------
// all fp32->bf16 conversions in ONE launch (6 ranges, if-chain)
// ---------------------------------------------------------------------------
__global__ __launch_bounds__(256) void conv_all(
        const float* __restrict__ s0, unsigned short* __restrict__ d0, long e0,
        const float* __restrict__ s1, unsigned short* __restrict__ d1, long e1,
        const float* __restrict__ s2, unsigned short* __restrict__ d2, long e2,
        const float* __restrict__ s3, unsigned short* __restrict__ d3, long e3,
        const float* __restrict__ s4, unsigned short* __restrict__ d4, long e4,
        const float* __restrict__ s5, unsigned short* __restrict__ d5) {
    long c = (long)blockIdx.x * 256 + threadIdx.x;   // 8-elem chunk index
    const float* src;
    unsigned short* dst;
    if      (c < e0) { src = s0; dst = d0; }
    else if (c < e1) { src = s1; dst = d1; c -= e0; }
    else if (c < e2) { src = s2; dst = d2; c -= e1; }
    else if (c < e3) { src = s3; dst = d3; c -= e2; }
    else if (c < e4) { src = s4; dst = d4; c -= e3; }
    else             { src = s5; dst = d5; c -= e4; }
    const float* p = src + c * 8;
    float4 a = *(const float4*)(p);
    float4 b = *(const float4*)(p + 4);
    union { short8 v; unsigned short u[8]; } t;
    t.u[0] = f2bf(a.x); t.u[1] = f2bf(a.y); t.u[2] = f2bf(a.z); t.u[3] = f2bf(a.w);
    t.u[4] = f2bf(b.x); t.u[5] = f2bf(b.y); t.u[6] = f2bf(b.z); t.u[7] = f2bf(b.w);
    *(short8*)&dst[c * 8] = t.v;
}

// ---------------------------------------------------------------------------
// bf16 MFMA GEMM:  C[M,N] = A[M,K] @ W[N,K]^T; OT = float or ushort(bf16) out.
// 128x128 tile, BK=64; global_load_lds width=16 staging with XOR swizzle.
// ---------------------------------------------------------------------------
#define GBM 128
#define GBN 128
#define GBK 64

template <typename OT>
__global__ __launch_bounds__(256) void gemm_t(const unsigned short* __restrict__ A,
                                              const unsigned short* __restrict__ W,
                                              OT* __restrict__ C,
                                              int M, int N, int K) {
    __shared__ unsigned short As[GBM * GBK];   // 16384 B
    __shared__ unsigned short Ws[GBN * GBK];   // 16384 B

    const int tid = threadIdx.x;
    const int w = tid >> 6, lane = tid & 63;
    const int l16 = lane & 15, quad = lane >> 4;
    const int wm = (w >> 1) * 64, wn = (w & 1) * 64;
    const int row0 = blockIdx.y * GBM, col0 = blockIdx.x * GBN;

    const int rL  = lane >> 3;
    const int c8g = (lane & 7) ^ rL;
    const int swzk[2] = { (((0 * 4) + quad) ^ (l16 & 7)) * 8,
                          (((1 * 4) + quad) ^ (l16 & 7)) * 8 };

    const float4v zf = {0.f, 0.f, 0.f, 0.f};
    float4v acc[4][4] = {{zf, zf, zf, zf}, {zf, zf, zf, zf},
                         {zf, zf, zf, zf}, {zf, zf, zf, zf}};

    for (int k0 = 0; k0 < K; k0 += GBK) {
        __syncthreads();
#pragma unroll
        for (int j = 0; j < 4; ++j) {
            const int ch = w * 4 + j;
            const int r = ch * 8 + rL;
            GLD16(&A[(size_t)(row0 + r) * K + k0 + c8g * 8], &As[ch * 512]);
            GLD16(&W[(size_t)(col0 + r) * K + k0 + c8g * 8], &Ws[ch * 512]);
        }
        __syncthreads();

#pragma unroll
        for (int kk = 0; kk < 2; ++kk) {
            const int swz = swzk[kk];
            short8 af[4], bf[4];
#pragma unroll
            for (int mi = 0; mi < 4; ++mi)
                af[mi] = *(const short8*)&As[(wm + mi * 16 + l16) * GBK + swz];
#pragma unroll
            for (int ni = 0; ni < 4; ++ni)
                bf[ni] = *(const short8*)&Ws[(wn + ni * 16 + l16) * GBK + swz];
#pragma unroll
            for (int mi = 0; mi < 4; ++mi)
#pragma unroll
                for (int ni = 0; ni < 4; ++ni)
                    acc[mi][ni] = __builtin_amdgcn_mfma_f32_16x16x32_bf16(af[mi], bf[ni], acc[mi][ni], 0, 0, 0);
        }
    }

#pragma unroll
    for (int mi = 0; mi < 4; ++mi)
#pragma unroll
        for (int ni = 0; ni < 4; ++ni)
#pragma unroll
            for (int r = 0; r < 4; ++r) {
                size_t idx = (size_t)(row0 + wm + mi * 16 + quad * 4 + r) * N + col0 + wn + ni * 16 + l16;
                if constexpr (sizeof(OT) == 2) C[idx] = f2bf(acc[mi][ni][r]);
                else                           C[idx] = acc[mi][ni][r];
            }
}

// ---------------------------------------------------------------------------
__global__ __launch_bounds__(256) void rmsnorm_b(const float* __restrict__ X,
                                                 const float* __restrict__ w,
                                                 unsigned short* __restrict__ Y,
                                                 int n, int ld) {
    __shared__ float tmp[4];
    const int row = blockIdx.x;
    const int tid = threadIdx.x;
    const float* x = X + (size_t)row * ld;

    float ss = 0.f;
    for (int c = tid; c < n; c += 256) {
        float v = x[c];
        ss = fmaf(v, v, ss);
    }
#pragma unroll
    for (int off = 32; off; off >>= 1) ss += __shfl_xor(ss, off, 64);
    if ((tid & 63) == 0) tmp[tid >> 6] = ss;
    __syncthreads();
    ss = tmp[0] + tmp[1] + tmp[2] + tmp[3];
    float r = rsqrtf(ss / (float)n + EPSF);

    for (int c = tid; c < n; c += 256)
        Y[(size_t)row * n + c] = f2bf(x[c] * r * w[c]);
}

// ---------------------------------------------------------------------------
__global__ __launch_bounds__(256) void kv_post(const float* __restrict__ KV,
                                               const float* __restrict__ w,
                                               const float* __restrict__ fc,
                                               unsigned short* __restrict__ kvcb,
                                               float* __restrict__ kpe,
                                               int ldkv) {
    __shared__ float tmp[4];
    const int row = blockIdx.x;
    const int s = row & (S_ - 1);
    const int tid = threadIdx.x;
    const float* kv = KV + (size_t)row * ldkv;

    float ss = 0.f;
#pragma unroll
    for (int c = tid; c < KVLORA; c += 256) {
        float v = kv[c];
        ss = fmaf(v, v, ss);
    }
#pragma unroll
    for (int off = 32; off; off >>= 1) ss += __shfl_xor(ss, off, 64);
    if ((tid & 63) == 0) tmp[tid >> 6] = ss;
    __syncthreads();
    ss = tmp[0] + tmp[1] + tmp[2] + tmp[3];
    float r = rsqrtf(ss / (float)KVLORA + EPSF);

#pragma unroll
    for (int c = tid; c < KVLORA; c += 256)
        kvcb[(size_t)row * KVLORA + c] = f2bf(kv[c] * r * w[c]);

    if (tid < 32) {
        int i = tid;
        float c0 = fc[(s * 32 + i) * 2 + 0];
        float s0 = fc[(s * 32 + i) * 2 + 1];
        float x0 = kv[KVLORA + 2 * i];
        float x1 = kv[KVLORA + 2 * i + 1];
        kpe[(size_t)row * DR + 2 * i]     = x0 * c0 - x1 * s0;
        kpe[(size_t)row * DR + 2 * i + 1] = x0 * s0 + x1 * c0;
    }
}

// ---------------------------------------------------------------------------
// pack_k: Kbf (B,H,S,192) bf16 from kvbb (M,H*256) bf16 + kpe (M,64) fp32
// ---------------------------------------------------------------------------
__global__ __launch_bounds__(256) void pack_k(const unsigned short* __restrict__ kvbb,
                                              const float* __restrict__ kpe,
                                              unsigned short* __restrict__ Kbf) {
    const int c = blockIdx.x * 256 + threadIdx.x;   // chunk of 8 elems
    const int total = B_ * H_ * S_ * (DQK / 8);
    if (c >= total) return;
    const int d8 = c % (DQK / 8);
    const int hs = c / (DQK / 8);
    const int s  = hs % S_;
    const int bh = hs / S_;
    const int b  = bh / H_;
    const int h  = bh % H_;
    const int d  = d8 * 8;
    const int row = b * S_ + s;

    short8 v;
    if (d < DN) {
        v = *(const short8*)&kvbb[(size_t)row * (H_ * 256) + h * 256 + d];
    } else {
        const float* src = kpe + (size_t)row * DR + (d - DN);
        float4 a = *(const float4*)(src);
        float4 bb = *(const float4*)(src + 4);
        union { short8 v; unsigned short u[8]; } t;
        t.u[0] = f2bf(a.x);  t.u[1] = f2bf(a.y);  t.u[2] = f2bf(a.z);  t.u[3] = f2bf(a.w);
        t.u[4] = f2bf(bb.x); t.u[5] = f2bf(bb.y); t.u[6] = f2bf(bb.z); t.u[7] = f2bf(bb.w);
        v = t.v;
    }
    *(short8*)&Kbf[(size_t)c * 8] = v;
}

// ---------------------------------------------------------------------------
// pack_vt: Vt (B,H,128,S) bf16 from kvbb (M,H*256) bf16 cols h*256+128..+256
// ---------------------------------------------------------------------------
__global__ __launch_bounds__(256) void pack_vt(const unsigned short* __restrict__ kvbb,
                                               unsigned short* __restrict__ Vt) {
    __shared__ unsigned short T[DV][72];
    const int st = blockIdx.x;            // seq tile (64)
    const int bh = blockIdx.y;            // b*H+h
    const int b = bh >> 4, h = bh & 15;
    const int s0 = st * 64;
    const int tid = threadIdx.x;

    for (int c = tid; c < 64 * 16; c += 256) {
        int sp = c >> 4, ch = c & 15;
        short8 v = *(const short8*)&kvbb[(size_t)(b * S_ + s0 + sp) * (H_ * 256) + h * 256 + DN + ch * 8];
        union { short8 v; unsigned short u[8]; } t; t.v = v;
        int dv = ch * 8;
#pragma unroll
        for (int e = 0; e < 8; ++e) T[dv + e][sp] = t.u[e];
    }
    __syncthreads();
    for (int c = tid; c < 128 * 8; c += 256) {
        int dv = c >> 3, ch = c & 7;
        *(short8*)&Vt[((size_t)bh * DV + dv) * S_ + s0 + ch * 8] = *(short8*)&T[dv][ch * 8];
    }
}

// ---------------------------------------------------------------------------
// MFMA flash attention (causal), bf16 in (q with fused RoPE), fp32 acc.
//
// v3 (occupancy fix over v2):
//  - v2's 4-wave/256-thread block left 1 wave/SIMD (100KB LDS -> 1 block/CU)
//    -> zero latency hiding, 8100 cy/k-tile vs ~900 cy floor. v3: 512
//    threads, 8 waves x 16 q-rows over the same 128-row q-tile -> 2
//    waves/SIMD, pipes overlap across waves, per-wave regs halve.
//  - keeps v2's wins: global_load_lds(16B) with XOR chunk swizzle (bank
//    conflicts 11.3M -> 0.5M), double-buffered K/V, counted vmcnt (5
//    loads/wave in flight across barriers), wave-private Ps, no mid barrier.
//  - Ps row stride 76 (was 72): 4-row quad spacing lands on distinct bank
//    octets for the b16 scatter writes (72 ≡ 8 mod 16 collided quads 0/2).
// ---------------------------------------------------------------------------
#define QTILES 16   // 2048 / 128
#define PROW 76

__global__ __launch_bounds__(512, 1) void flash_mfma(const unsigned short* __restrict__ Qb,
                                                     const float* __restrict__ fc,
                                                     const unsigned short* __restrict__ Kbf,
                                                     const unsigned short* __restrict__ Vt,
                                                     unsigned short* __restrict__ Ob) {
    __shared__ unsigned short Ks[2][64 * 192];    // 2 x 24576 B, swizzled chunks
    __shared__ unsigned short Vs[2][128 * 64];    // 2 x 16384 B, swizzled chunks
    __shared__ unsigned short Ps[8][16][PROW];    // 19456 B, wave-private P

    const int bh = blockIdx.x;                  // b*H+h
    const int bx = blockIdx.y;                  // 0..7 pair index
    const int b = bh >> 4, h = bh & 15;
    const int tid = threadIdx.x;
    const int w = tid >> 6, lane = tid & 63;
    const int l16 = lane & 15, quad = lane >> 4;
    const int sw = l16 & 7;                     // read-side swizzle key

    const unsigned short* Kg = Kbf + (size_t)bh * S_ * DQK;
    const unsigned short* Vg = Vt + (size_t)bh * DV * S_;

    // stage K/V tile kt_ into buffer bufi: 5 global_load_lds per wave.
    // chunk c of row r stored at (seg*64+lane)*16B, fetched from swizzled col.
    auto stage = [&](int kt_, int bufi) {
        const int kb_ = kt_ * 64;
#pragma unroll
        for (int i_ = 0; i_ < 3; ++i_) {             // K: 64 rows x 24 chunks
            int ch = (w * 3 + i_) * 64 + lane;
            int r_ = ch / 24, c_ = ch - r_ * 24;
            GLD16(&Kg[(size_t)(kb_ + r_) * DQK + ((c_ ^ (r_ & 7)) << 3)],
                  &Ks[bufi][(w * 3 + i_) * 512]);
        }
#pragma unroll
        for (int i_ = 0; i_ < 2; ++i_) {             // V: 128 rows x 8 chunks
            int ch = (w * 2 + i_) * 64 + lane;
            int r_ = ch >> 3, c_ = ch & 7;
            GLD16(&Vg[(size_t)r_ * S_ + kb_ + ((c_ ^ (r_ & 7)) << 3)],
                  &Vs[bufi][(w * 2 + i_) * 512]);
        }
    };

    for (int half = 0; half < 2; ++half) {
        const int qt = half ? (QTILES - 1 - bx) : bx;
        const int q0 = qt * 128;
        const int ntiles = 2 * qt + 2;          // always even -> buf parity ok
        const int wr0 = q0 + w * 16;            // wave's first q row

        stage(0, 0);                            // tile 0 DMA in flight

        // Q A-frags (16 rows/wave), RoPE fused for d >= 128
        short8 a_q[6];
        {
            const int s = wr0 + l16;
            const unsigned short* qrow = Qb + (size_t)(b * S_ + s) * (H_ * DQK) + h * DQK;
#pragma unroll
            for (int i = 0; i < 6; ++i) {
                short8 t = *(const short8*)&qrow[i * 32 + quad * 8];
                if (i >= 4) {
                    union { short8 v; unsigned short u[8]; } x; x.v = t;
#pragma unroll
                    for (int j = 0; j < 4; ++j) {
                        int ip = (i - 4) * 16 + quad * 4 + j;
                        float c0 = fc[(s * 32 + ip) * 2 + 0];
                        float s0 = fc[(s * 32 + ip) * 2 + 1];
                        float x0 = bf2f(x.u[2 * j]);
                        float x1 = bf2f(x.u[2 * j + 1]);
                        x.u[2 * j]     = f2bf(x0 * c0 - x1 * s0);
                        x.u[2 * j + 1] = f2bf(x0 * s0 + x1 * c0);
                    }
                    t = x.v;
                }
                a_q[i] = t;
            }
        }

        const float4v zf = {0.f, 0.f, 0.f, 0.f};
        float4v o_acc[8] = {zf, zf, zf, zf, zf, zf, zf, zf};
        float l_r[4] = {0.f, 0.f, 0.f, 0.f};

        int buf = 0;
        for (int kt = 0; kt < ntiles; ++kt) {
            const int kb = kt * 64;

            // barrier 1: everyone done computing kt-1 -> buf^1 overwritable
            __builtin_amdgcn_s_barrier();
            if (kt + 1 < ntiles) {
                stage(kt + 1, buf ^ 1);
                asm volatile("s_waitcnt vmcnt(5)" ::: "memory");   // own kt loads done
            } else {
                asm volatile("s_waitcnt vmcnt(0)" ::: "memory");
            }
            __builtin_amdgcn_sched_barrier(0);
            // barrier 2: everyone's kt loads landed
            __builtin_amdgcn_s_barrier();
            __builtin_amdgcn_sched_barrier(0);

            if (kb <= wr0 + 15) {               // wave not fully causal-masked
                const unsigned short* Kb_ = Ks[buf];
                const unsigned short* Vb_ = Vs[buf];

                // QK^T: 24 ds_read_b128 -> 24 mfma (4 independent acc chains)
                float4v sc[4] = {zf, zf, zf, zf};
#pragma unroll
                for (int i = 0; i < 6; ++i) {
                    short8 bk[4];
#pragma unroll
                    for (int kg = 0; kg < 4; ++kg)
                        bk[kg] = *(const short8*)&Kb_[(kg * 16 + l16) * 192 + (((i * 4 + quad) ^ sw) << 3)];
#pragma unroll
                    for (int kg = 0; kg < 4; ++kg)
                        sc[kg] = __builtin_amdgcn_mfma_f32_16x16x32_bf16(a_q[i], bk[kg], sc[kg], 0, 0, 0);
                }

                // max-free softmax (mask post-exp; wave-uniform mneed branch)
                const bool mneed = (kb + 63 > wr0);
#pragma unroll
                for (int kg = 0; kg < 4; ++kg) {
                    const int key = kb + kg * 16 + l16;
#pragma unroll
                    for (int r = 0; r < 4; ++r) {
                        float p = __expf(sc[kg][r] * SCALEF);
                        if (mneed && key > wr0 + quad * 4 + r) p = 0.f;
                        l_r[r] += p;
                        Ps[w][quad * 4 + r][kg * 16 + l16] = f2bf(p);
                    }
                }

                // PV: Ps is wave-private -> no barrier needed before reads
#pragma unroll
                for (int kc = 0; kc < 2; ++kc) {
                    short8 pa = *(const short8*)&Ps[w][l16][kc * 32 + quad * 8];
#pragma unroll
                    for (int dvt = 0; dvt < 8; ++dvt) {
                        short8 vb = *(const short8*)&Vb_[(dvt * 16 + l16) * 64 + (((kc * 4 + quad) ^ sw) << 3)];
                        o_acc[dvt] = __builtin_amdgcn_mfma_f32_16x16x32_bf16(pa, vb, o_acc[dvt], 0, 0, 0);
                    }
                }
            }
            buf ^= 1;
        }

        // epilogue: reduce l over the 16 key-lanes, write O
#pragma unroll
        for (int r = 0; r < 4; ++r) {
            float t = l_r[r];
            t += __shfl_xor(t, 1);
            t += __shfl_xor(t, 2);
            t += __shfl_xor(t, 4);
            t += __shfl_xor(t, 8);
            l_r[r] = t;
        }
#pragma unroll
        for (int r = 0; r < 4; ++r) {
            float inv = 1.f / l_r[r];
            int row = wr0 + quad * 4 + r;
            unsigned short* op = Ob + (size_t)(b * S_ + row) * (H_ * DV) + h * DV;
#pragma unroll
            for (int dvt = 0; dvt < 8; ++dvt)
                op[dvt * 16 + l16] = f2bf(o_acc[dvt][r] * inv);
        }
    }
}

// ---------------------------------------------------------------------------
extern "C" void kernel_launch(void* const* d_in, const int* in_sizes, int n_in,
                              void* d_out, int out_size, void* d_ws, size_t ws_size,
                              hipStream_t stream) {
    const float* x    = (const float*)d_in[0];
    const float* fc   = (const float*)d_in[1];
    const float* Wqa  = (const float*)d_in[2];
    const float* qlw  = (const float*)d_in[3];
    const float* Wqb  = (const float*)d_in[4];
    const float* Wkva = (const float*)d_in[5];
    const float* kvw  = (const float*)d_in[6];
    const float* Wkvb = (const float*)d_in[7];
    const float* Wo   = (const float*)d_in[8];
    float* out = (float*)d_out;

    const int M = B_ * S_;                 // 4096
    const int NQKV = QLORA + 640;          // 2176
    char* wsb = (char*)d_ws;

    // R1 (50331648 B): qb bf16 (25165824) + Wob (8388608)
    unsigned short* qb  = (unsigned short*)wsb;
    unsigned short* Wob = (unsigned short*)(wsb + 25165824);
    // R2 (67108864 B)
    char* R2 = wsb + 50331648;
    float*          qlkv  = (float*)R2;                          // 35651584
    unsigned short* xb    = (unsigned short*)(R2 + 35651584);    // 16777216
    unsigned short* Wcat  = (unsigned short*)(R2 + 52428800);    //  8912896
    unsigned short* kvbb  = (unsigned short*)R2;                 // 33554432 (after qlkv dead)
    unsigned short* attnb = (unsigned short*)R2;                 // 16777216 (after packs)
    // R3 (25165824 B)
    char* R3 = R2 + 67108864;
    unsigned short* qlatb = (unsigned short*)R3;                 // 12582912
    unsigned short* Wqbb  = (unsigned short*)(R3 + 12582912);    //  9437184
    unsigned short* Kbf   = (unsigned short*)R3;                 // 25165824 (after q-gemm)
    // R4 (16777216 B)
    char* R4 = R3 + 25165824;
    float*          kpe   = (float*)R4;                          //  1048576
    unsigned short* kvcb  = (unsigned short*)(R4 + 1048576);     //  4194304
    unsigned short* Wkvbb = (unsigned short*)(R4 + 5242880);     //  4194304
    unsigned short* Vt    = (unsigned short*)R4;                 // 16777216 (after pack_k)

    // 0) single mega-conversion: x, Wqa, Wkva, Wqb, Wkvb, Wo
    {
        const long e0 = 1048576;           // x      (M*D/8)
        const long e1 = e0 + 393216;       // Wqa    (1536*2048/8)
        const long e2 = e1 + 147456;       // Wkva   (576*2048/8)
        const long e3 = e2 + 589824;       // Wqb    (3072*1536/8)
        const long e4 = e3 + 262144;       // Wkvb   (4096*512/8)
        const long tot = e4 + 524288;      // Wo     (2048*2048/8) -> 2965504
        conv_all<<<(int)(tot / 256), 256, 0, stream>>>(
            x, xb, e0,
            Wqa, Wcat, e1,
            Wkva, Wcat + (size_t)QLORA * D_, e2,
            Wqb, Wqbb, e3,
            Wkvb, Wkvbb, e4,
            Wo, Wob);
    }

    // 1) merged: qlkv = xb @ Wcat^T (cols 0..1535 = qlat, 1536..2111 = kvraw)
    gemm_t<float><<<dim3(NQKV / GBN, M / GBM), 256, 0, stream>>>(xb, Wcat, qlkv, M, NQKV, D_);

    // 2) norms (emit bf16) + k_pe rope
    rmsnorm_b<<<M, 256, 0, stream>>>(qlkv, qlw, qlatb, QLORA, NQKV);
    kv_post<<<M, 256, 0, stream>>>(qlkv + QLORA, kvw, fc, kvcb, kpe, NQKV);

    // 3) qb = qlatb @ Wqbb^T (bf16 out; RoPE fused into flash Q load)
    //    kvbb = kvcb @ Wkvbb^T (bf16 out)
    gemm_t<unsigned short><<<dim3(H_ * DQK / GBN, M / GBM), 256, 0, stream>>>(qlatb, Wqbb, qb, M, H_ * DQK, QLORA);
    gemm_t<unsigned short><<<dim3(H_ * 256 / GBN, M / GBM), 256, 0, stream>>>(kvcb, Wkvbb, kvbb, M, H_ * 256, KVLORA);

    // 4) pack K then V (pack_k reads kpe which Vt overwrites -> strict order)
    {
        int total = B_ * H_ * S_ * (DQK / 8);
        pack_k<<<(total + 255) / 256, 256, 0, stream>>>(kvbb, kpe, Kbf);
        pack_vt<<<dim3(S_ / 64, B_ * H_), 256, 0, stream>>>(kvbb, Vt);
    }

    // 5) flash attention: 128-row q-tiles, 8 waves x 16 q-rows, pairs (bx,15-bx)
    flash_mfma<<<dim3(B_ * H_, QTILES / 2), 512, 0, stream>>>(qb, fc, Kbf, Vt, attnb);

    // 6) out = attnb @ Wob^T
    gemm_t<float><<<dim3(D_ / GBN, M / GBM), 256, 0, stream>>>(attnb, Wob, out, M, D_, D_);
}